// Round 9
// baseline (416.192 us; speedup 1.0000x reference)
//
#include <hip/hip_runtime.h>
#include <hip/hip_bf16.h>

typedef __attribute__((ext_vector_type(8))) __bf16 bf16x8;
typedef __attribute__((ext_vector_type(4))) float f32x4;

#define DEVI static __device__ __forceinline__

// ---- helpers ---------------------------------------------------------------

DEVI ushort f2bf(float f) {
  unsigned u = __builtin_bit_cast(unsigned, f);
  return (ushort)((u + 0x7fffu + ((u >> 16) & 1u)) >> 16);
}

union BF8 { unsigned u[4]; bf16x8 v; };

DEVI bf16x8 cvt8(const float* __restrict__ p) {
  const f32x4 a = *(const f32x4*)p;
  const f32x4 b = *(const f32x4*)(p + 4);
  BF8 r;
  asm("v_cvt_pk_bf16_f32 %0, %1, %2" : "=v"(r.u[0]) : "v"(a.x), "v"(a.y));
  asm("v_cvt_pk_bf16_f32 %0, %1, %2" : "=v"(r.u[1]) : "v"(a.z), "v"(a.w));
  asm("v_cvt_pk_bf16_f32 %0, %1, %2" : "=v"(r.u[2]) : "v"(b.x), "v"(b.y));
  asm("v_cvt_pk_bf16_f32 %0, %1, %2" : "=v"(r.u[3]) : "v"(b.z), "v"(b.w));
  return r.v;
}

DEVI void gload16(const void* g, void* l) {
  __builtin_amdgcn_global_load_lds(
      (const __attribute__((address_space(1))) unsigned*)g,
      (__attribute__((address_space(3))) unsigned*)l, 16, 0, 0);
}

DEVI int xcd_swizzle(int bid, int nwg) {
  return (bid & 7) * (nwg >> 3) + (bid >> 3);
}

// ---- f32 -> bf16 convert: exactly 4 chunks of 8 elems per thread -----------

__global__ __launch_bounds__(256) void cvt4(
    const float* __restrict__ in, ushort* __restrict__ out) {
  const unsigned G = gridDim.x * 256;
  const unsigned t = blockIdx.x * 256 + threadIdx.x;
#pragma unroll
  for (int j = 0; j < 4; ++j) {
    const size_t i = (size_t)t + (size_t)j * G;
    *(bf16x8*)(out + i * 8) = cvt8(in + i * 8);
  }
}

// ---- GEMM: BM=256, BN=128, BK=64, depth-3 rotating LDS, 512 threads --------
// 8 waves (4M x 2N), per-wave 64x64 output, 32 MFMA/K-tile as 2 phases of 16.
// Staging: K-tile i+2 issued during iter i (3 gloads/phase); counted
// vmcnt(9/6/0) at phase 0 drains exactly K-tile i (loads 4-8 phases old).
// LDS: A[3][256x64] + B[3][128x64] bf16 = 144 KB. Full 8-slot XOR swizzle:
// LDS(row, slot) holds global slot^(row&7); ds_read applies the same XOR ->
// every consecutive-8-lane group covers 8 distinct 16B slots (conflict-free).

template <int OUT_BF16>
__global__ __launch_bounds__(512, 1) void gemm_t3(
    const ushort* __restrict__ A, const ushort* __restrict__ B,
    const float* __restrict__ bias, void* __restrict__ Cp, int N, int K) {
  __shared__ __align__(16) ushort Asm[3][16384];  // 3 x 32 KB
  __shared__ __align__(16) ushort Bsm[3][8192];   // 3 x 16 KB
  const int tid = threadIdx.x, lane = tid & 63;
  const int wv = tid >> 6;
  const int wr = wv >> 1, wc = wv & 1;  // 4 M-waves x 2 N-waves
  const int cc = lane & 15, cr = lane >> 4;
  const int nw = N >> 7;
  const int work = xcd_swizzle(blockIdx.x, gridDim.x);
  const size_t m0 = (size_t)(work / nw) * 256;
  const size_t n0 = (size_t)(work % nw) * 128;

  // staging maps: thread t handles LDS 16B unit t of each 8KB chunk
  const int r3 = tid >> 3;                           // row-in-chunk 0..63
  const int sg8 = (((tid & 7) ^ (r3 & 7)) << 3);     // pre-swizzled col elems
  const ushort* Ag = A + (m0 + r3) * (size_t)K + sg8;
  const ushort* Bg = B + (n0 + r3) * (size_t)K + sg8;
  ushort* Al = &Asm[0][0] + tid * 8;
  ushort* Bl = &Bsm[0][0] + tid * 8;

  auto stA = [&](int buf, int kt, int c) {
    gload16(Ag + (size_t)(c * 64) * K + kt, Al + buf * 16384 + c * 4096);
  };
  auto stB = [&](int buf, int kt, int c) {
    gload16(Bg + (size_t)(c * 64) * K + kt, Bl + buf * 8192 + c * 4096);
  };

  f32x4 acc[4][4] = {};
  bf16x8 bfr[4][2];
  const int nt = K >> 6;  // 16

  // prologue: K-tile 0 -> buf0, K-tile 1 -> buf1 (6 gloads each)
#pragma unroll
  for (int c = 0; c < 4; ++c) stA(0, 0, c);
  stB(0, 0, 0); stB(0, 0, 1);
#pragma unroll
  for (int c = 0; c < 4; ++c) stA(1, 64, c);
  stB(1, 64, 0); stB(1, 64, 1);

  for (int i = 0; i < nt; ++i) {
    const int r = i % 3;
    const int rn = (i + 2) % 3;
    const ushort* Ab = &Asm[r][0];
    const ushort* Bb = &Bsm[r][0];

    // ---- phase 0: stage 3, counted wait, B-frags + A-pair0, 16 MFMA ----
    if (i + 2 < nt) {
      const int kt = (i + 2) << 6;
      stA(rn, kt, 0); stA(rn, kt, 1); stB(rn, kt, 0);
      asm volatile("s_waitcnt vmcnt(9)" ::: "memory");
    } else if (i + 1 < nt) {
      asm volatile("s_waitcnt vmcnt(6)" ::: "memory");
    } else {
      asm volatile("s_waitcnt vmcnt(0)" ::: "memory");
    }
    __builtin_amdgcn_s_barrier();
    asm volatile("" ::: "memory");

    bf16x8 af[2][2];
#pragma unroll
    for (int n = 0; n < 4; ++n) {
      const int row = wc * 64 + n * 16 + cc;
      bfr[n][0] = *(const bf16x8*)&Bb[row * 64 + (((cr) ^ (row & 7)) << 3)];
      bfr[n][1] = *(const bf16x8*)&Bb[row * 64 + (((4 + cr) ^ (row & 7)) << 3)];
    }
#pragma unroll
    for (int mm = 0; mm < 2; ++mm) {
      const int row = wr * 64 + mm * 16 + cc;
      af[mm][0] = *(const bf16x8*)&Ab[row * 64 + (((cr) ^ (row & 7)) << 3)];
      af[mm][1] = *(const bf16x8*)&Ab[row * 64 + (((4 + cr) ^ (row & 7)) << 3)];
    }
    asm volatile("s_waitcnt lgkmcnt(0)" ::: "memory");
    __builtin_amdgcn_s_setprio(1);
#pragma unroll
    for (int mm = 0; mm < 2; ++mm)
#pragma unroll
      for (int n = 0; n < 4; ++n) {
        acc[mm][n] = __builtin_amdgcn_mfma_f32_16x16x32_bf16(
            af[mm][0], bfr[n][0], acc[mm][n], 0, 0, 0);
        acc[mm][n] = __builtin_amdgcn_mfma_f32_16x16x32_bf16(
            af[mm][1], bfr[n][1], acc[mm][n], 0, 0, 0);
      }
    __builtin_amdgcn_s_setprio(0);
    asm volatile("" ::: "memory");
    __builtin_amdgcn_s_barrier();

    // ---- phase 1: stage 3, A-pair1, 16 MFMA ----
    if (i + 2 < nt) {
      const int kt = (i + 2) << 6;
      stA(rn, kt, 2); stA(rn, kt, 3); stB(rn, kt, 1);
    }
#pragma unroll
    for (int mm = 0; mm < 2; ++mm) {
      const int row = wr * 64 + (2 + mm) * 16 + cc;
      af[mm][0] = *(const bf16x8*)&Ab[row * 64 + (((cr) ^ (row & 7)) << 3)];
      af[mm][1] = *(const bf16x8*)&Ab[row * 64 + (((4 + cr) ^ (row & 7)) << 3)];
    }
    asm volatile("s_waitcnt lgkmcnt(0)" ::: "memory");
    __builtin_amdgcn_s_setprio(1);
#pragma unroll
    for (int mm = 0; mm < 2; ++mm)
#pragma unroll
      for (int n = 0; n < 4; ++n) {
        acc[2 + mm][n] = __builtin_amdgcn_mfma_f32_16x16x32_bf16(
            af[mm][0], bfr[n][0], acc[2 + mm][n], 0, 0, 0);
        acc[2 + mm][n] = __builtin_amdgcn_mfma_f32_16x16x32_bf16(
            af[mm][1], bfr[n][1], acc[2 + mm][n], 0, 0, 0);
      }
    __builtin_amdgcn_s_setprio(0);
    asm volatile("" ::: "memory");
    __builtin_amdgcn_s_barrier();
  }

  // epilogue
#pragma unroll
  for (int n = 0; n < 4; ++n) {
    const size_t col = n0 + wc * 64 + n * 16 + cc;
    const float bval = bias[col];
#pragma unroll
    for (int m = 0; m < 4; ++m) {
      const size_t row0 = m0 + wr * 64 + m * 16 + cr * 4;
#pragma unroll
      for (int r = 0; r < 4; ++r) {
        const float val = acc[m][n][r] + bval;
        if constexpr (OUT_BF16)
          ((ushort*)Cp)[(row0 + r) * N + col] = f2bf(val);
        else
          ((float*)Cp)[(row0 + r) * N + col] = val;
      }
    }
  }
}

// ---- windowed attention ----------------------------------------------------
// grid = B*H*NW = 1024 blocks, 256 threads (4 waves x 64 q-rows).
// q/k/v: bf16 [B*S, D] with col = h*64+dk. Output written in-place over q.

__global__ __launch_bounds__(256) void attn_kernel(
    const ushort* __restrict__ q, const ushort* __restrict__ k,
    const ushort* __restrict__ v, ushort* __restrict__ x) {
  __shared__ ushort Ks[256 * 72];
  __shared__ ushort Vt[64 * 264];
  __shared__ ushort Pw[4][16 * 264];
  const int bid = blockIdx.x;
  const int w = bid & 15, h = (bid >> 4) & 15, b = bid >> 8;
  const int tid = threadIdx.x, lane = tid & 63, wv = tid >> 6;
  const int cc = lane & 15, cr = lane >> 4;
  const size_t base = ((size_t)b * 4096 + (size_t)w * 256) * 1024 + h * 64;

#pragma unroll
  for (int i = 0; i < 8; ++i) {
    const int ch = i * 256 + tid;
    const int row = ch >> 3, kc = ch & 7;
    bf16x8 val = *(const bf16x8*)(k + base + (size_t)row * 1024 + kc * 8);
    *(bf16x8*)&Ks[row * 72 + kc * 8] = val;
  }
  {
    const ushort* vp = v + base + (size_t)tid * 1024;
#pragma unroll
    for (int j = 0; j < 8; ++j) {
      bf16x8 vvv = *(const bf16x8*)(vp + j * 8);
#pragma unroll
      for (int e = 0; e < 8; ++e)
        Vt[(j * 8 + e) * 264 + tid] = __builtin_bit_cast(ushort, (__bf16)vvv[e]);
    }
  }
  __syncthreads();

  ushort* Pp = Pw[wv];
  for (int c = 0; c < 4; ++c) {
    const int qrow0 = wv * 64 + c * 16;
    const ushort* qp = q + base + (size_t)(qrow0 + cc) * 1024 + cr * 8;
    const bf16x8 qf0 = *(const bf16x8*)qp;
    const bf16x8 qf1 = *(const bf16x8*)(qp + 32);

    f32x4 sc[16];
#pragma unroll
    for (int cb = 0; cb < 16; ++cb) {
      const bf16x8 kb0 = *(const bf16x8*)&Ks[(cb * 16 + cc) * 72 + cr * 8];
      const bf16x8 kb1 = *(const bf16x8*)&Ks[(cb * 16 + cc) * 72 + 32 + cr * 8];
      f32x4 z = {0.f, 0.f, 0.f, 0.f};
      z = __builtin_amdgcn_mfma_f32_16x16x32_bf16(qf0, kb0, z, 0, 0, 0);
      z = __builtin_amdgcn_mfma_f32_16x16x32_bf16(qf1, kb1, z, 0, 0, 0);
      sc[cb] = z;
    }

    float inv[4];
#pragma unroll
    for (int r = 0; r < 4; ++r) {
      float mx = -1e30f;
#pragma unroll
      for (int cb = 0; cb < 16; ++cb) mx = fmaxf(mx, sc[cb][r]);
      mx = fmaxf(mx, __shfl_xor(mx, 1));
      mx = fmaxf(mx, __shfl_xor(mx, 2));
      mx = fmaxf(mx, __shfl_xor(mx, 4));
      mx = fmaxf(mx, __shfl_xor(mx, 8));
      float sum = 0.f;
#pragma unroll
      for (int cb = 0; cb < 16; ++cb) {
        const float p = __expf((sc[cb][r] - mx) * 0.125f);
        sc[cb][r] = p;
        sum += p;
      }
      sum += __shfl_xor(sum, 1);
      sum += __shfl_xor(sum, 2);
      sum += __shfl_xor(sum, 4);
      sum += __shfl_xor(sum, 8);
      inv[r] = 1.f / sum;
    }

#pragma unroll
    for (int r = 0; r < 4; ++r)
#pragma unroll
      for (int cb = 0; cb < 16; ++cb)
        Pp[(cr * 4 + r) * 264 + cb * 16 + cc] = f2bf(sc[cb][r]);

    bf16x8 pf[8];
#pragma unroll
    for (int ks = 0; ks < 8; ++ks)
      pf[ks] = *(const bf16x8*)&Pp[cc * 264 + ks * 32 + cr * 8];
    f32x4 o[4] = {};
#pragma unroll
    for (int db = 0; db < 4; ++db)
#pragma unroll
      for (int ks = 0; ks < 8; ++ks) {
        const bf16x8 bv = *(const bf16x8*)&Vt[(db * 16 + cc) * 264 + ks * 32 + cr * 8];
        o[db] = __builtin_amdgcn_mfma_f32_16x16x32_bf16(pf[ks], bv, o[db], 0, 0, 0);
      }

#pragma unroll
    for (int db = 0; db < 4; ++db)
#pragma unroll
      for (int r = 0; r < 4; ++r) {
        const int qr = qrow0 + cr * 4 + r;
        x[base + (size_t)qr * 1024 + db * 16 + cc] = f2bf(o[db][r] * inv[r]);
      }
  }
}

// ---- launch ----------------------------------------------------------------

extern "C" void kernel_launch(void* const* d_in, const int* in_sizes, int n_in,
                              void* d_out, int out_size, void* d_ws, size_t ws_size,
                              hipStream_t stream) {
  const float* query = (const float*)d_in[0];
  const float* key_  = (const float*)d_in[1];
  const float* value = (const float*)d_in[2];
  const float* Wq = (const float*)d_in[3];
  const float* bq = (const float*)d_in[4];
  const float* Wk = (const float*)d_in[5];
  const float* bk = (const float*)d_in[6];
  const float* Wv = (const float*)d_in[7];
  const float* bv = (const float*)d_in[8];
  const float* Wo = (const float*)d_in[9];
  const float* bo = (const float*)d_in[10];
  float* out = (float*)d_out;

  // ws: qb/kb/vb bf16 input copies + 4 bf16 weights + qp/kp/vp projections
  const size_t MN = (size_t)16384 * 1024;
  const size_t WN = (size_t)1024 * 1024;
  ushort* qb = (ushort*)d_ws;
  ushort* kb = qb + MN;
  ushort* vb = kb + MN;
  ushort* wqb = vb + MN;
  ushort* wkb = wqb + WN;
  ushort* wvb = wkb + WN;
  ushort* wob = wvb + WN;
  ushort* qp = wob + WN;
  ushort* kp = qp + MN;
  ushort* vp = kp + MN;

  const dim3 b256(256), b512(512);
  const dim3 ggrid(512);  // (16384/256) * (1024/128)

  cvt4<<<dim3(2048), b256, 0, stream>>>(query, qb);
  cvt4<<<dim3(2048), b256, 0, stream>>>(key_, kb);
  cvt4<<<dim3(2048), b256, 0, stream>>>(value, vb);
  cvt4<<<dim3(128), b256, 0, stream>>>(Wq, wqb);
  cvt4<<<dim3(128), b256, 0, stream>>>(Wk, wkb);
  cvt4<<<dim3(128), b256, 0, stream>>>(Wv, wvb);
  cvt4<<<dim3(128), b256, 0, stream>>>(Wo, wob);

  gemm_t3<1><<<ggrid, b512, 0, stream>>>(qb, wqb, bq, qp, 1024, 1024);
  gemm_t3<1><<<ggrid, b512, 0, stream>>>(kb, wkb, bk, kp, 1024, 1024);
  gemm_t3<1><<<ggrid, b512, 0, stream>>>(vb, wvb, bv, vp, 1024, 1024);

  attn_kernel<<<dim3(1024), b256, 0, stream>>>(qp, kp, vp, qp /*in-place*/);

  gemm_t3<0><<<ggrid, b512, 0, stream>>>(qp, wob, bo, out, 1024, 1024);
}

// Round 10
// 349.335 us; speedup vs baseline: 1.1914x; 1.1914x over previous
//
#include <hip/hip_runtime.h>
#include <hip/hip_bf16.h>

typedef __attribute__((ext_vector_type(8))) __bf16 bf16x8;
typedef __attribute__((ext_vector_type(4))) float f32x4;

#define DEVI static __device__ __forceinline__

// ---- helpers ---------------------------------------------------------------

DEVI ushort f2bf(float f) {
  unsigned u = __builtin_bit_cast(unsigned, f);
  return (ushort)((u + 0x7fffu + ((u >> 16) & 1u)) >> 16);
}

union BF8 { unsigned u[4]; bf16x8 v; };

DEVI bf16x8 cvt8(const float* __restrict__ p) {
  const f32x4 a = *(const f32x4*)p;
  const f32x4 b = *(const f32x4*)(p + 4);
  BF8 r;
  asm("v_cvt_pk_bf16_f32 %0, %1, %2" : "=v"(r.u[0]) : "v"(a.x), "v"(a.y));
  asm("v_cvt_pk_bf16_f32 %0, %1, %2" : "=v"(r.u[1]) : "v"(a.z), "v"(a.w));
  asm("v_cvt_pk_bf16_f32 %0, %1, %2" : "=v"(r.u[2]) : "v"(b.x), "v"(b.y));
  asm("v_cvt_pk_bf16_f32 %0, %1, %2" : "=v"(r.u[3]) : "v"(b.z), "v"(b.w));
  return r.v;
}

DEVI void gload16(const void* g, void* l) {
  __builtin_amdgcn_global_load_lds(
      (const __attribute__((address_space(1))) unsigned*)g,
      (__attribute__((address_space(3))) unsigned*)l, 16, 0, 0);
}

DEVI int xcd_swizzle(int bid, int nwg) {
  return (bid & 7) * (nwg >> 3) + (bid >> 3);
}

// ---- converts: block-uniform tensor select, 4 chunks of 8 per thread -------

__global__ __launch_bounds__(256) void cvt_qkv(
    const float* __restrict__ q, const float* __restrict__ k,
    const float* __restrict__ v, ushort* __restrict__ oq,
    ushort* __restrict__ ok2, ushort* __restrict__ ov) {
  const int s = blockIdx.x >> 11;          // 0..2 (uniform per block)
  const int tb = blockIdx.x & 2047;
  const float* src = s == 0 ? q : (s == 1 ? k : v);
  ushort* dst = s == 0 ? oq : (s == 1 ? ok2 : ov);
  const unsigned G = 2048 * 256;
  const unsigned t = tb * 256 + threadIdx.x;
#pragma unroll
  for (int j = 0; j < 4; ++j) {
    const size_t i = (size_t)t + (size_t)j * G;
    *(bf16x8*)(dst + i * 8) = cvt8(src + i * 8);
  }
}

__global__ __launch_bounds__(256) void cvt_w(
    const float* __restrict__ wq, const float* __restrict__ wk,
    const float* __restrict__ wv, const float* __restrict__ wo,
    ushort* __restrict__ oq, ushort* __restrict__ ok2,
    ushort* __restrict__ ov, ushort* __restrict__ oo) {
  const int s = blockIdx.x >> 7;           // 0..3
  const int tb = blockIdx.x & 127;
  const float* src = s == 0 ? wq : (s == 1 ? wk : (s == 2 ? wv : wo));
  ushort* dst = s == 0 ? oq : (s == 1 ? ok2 : (s == 2 ? ov : oo));
  const unsigned G = 128 * 256;
  const unsigned t = tb * 256 + threadIdx.x;
#pragma unroll
  for (int j = 0; j < 4; ++j) {
    const size_t i = (size_t)t + (size_t)j * G;
    *(bf16x8*)(dst + i * 8) = cvt8(src + i * 8);
  }
}

// ---- GEMM (bf16 x bf16): C[M,N] = A @ W^T + bias ---------------------------
// 128x128 tile, BK=32, 256 threads (4 waves), 2-phase double-buffered LDS:
// STAGE(t+1) before computing tile t; counted vmcnt(4) + raw s_barrier keeps
// next-tile loads in flight under compute. 32 KB LDS -> 4-5 blocks/CU, whose
// interleaved barriers hide the per-block stalls (measured best structure
// for M=16384/N=1024/K=1024: ~60 us, vs 82 us for 256x128 BK=64 depth-3).

template <int OUT_BF16>
__global__ __launch_bounds__(256) void gemm_2ph(
    const ushort* __restrict__ A, const ushort* __restrict__ B,
    const float* __restrict__ bias, void* __restrict__ Cp, int N, int K) {
  __shared__ __align__(16) ushort As[2][128 * 32];
  __shared__ __align__(16) ushort Bs[2][128 * 32];
  const int tid = threadIdx.x, lane = tid & 63;
  const int wv = tid >> 6, wr = wv >> 1, wc = wv & 1;
  const int cc = lane & 15, cr = lane >> 4;
  const int ntiles = N >> 7;
  const int work = xcd_swizzle(blockIdx.x, gridDim.x);
  const size_t m0 = (size_t)(work / ntiles) * 128;
  const size_t n0 = (size_t)(work % ntiles) * 128;

  // 512 chunks of 8 bf16 per tile, 2 per thread; pre-swizzled source so
  // linear LDS dest + swizzled ds_read are conflict-free (both-sides rule)
  const int ch0 = tid, ch1 = tid + 256;
  const int row0 = ch0 >> 2, u0 = ch0 & 3;
  const int row1 = ch1 >> 2, u1 = ch1 & 3;
  const int sw0 = (u0 ^ ((row0 >> 1) & 3)) * 8;
  const int sw1 = (u1 ^ ((row1 >> 1) & 3)) * 8;
  const ushort* a0 = A + (m0 + row0) * (size_t)K + sw0;
  const ushort* a1 = A + (m0 + row1) * (size_t)K + sw1;
  const ushort* b0 = B + (n0 + row0) * (size_t)K + sw0;
  const ushort* b1 = B + (n0 + row1) * (size_t)K + sw1;

  auto stage = [&](int bf, int kt) {
    gload16(a0 + kt, &As[bf][ch0 * 8]);
    gload16(a1 + kt, &As[bf][ch1 * 8]);
    gload16(b0 + kt, &Bs[bf][ch0 * 8]);
    gload16(b1 + kt, &Bs[bf][ch1 * 8]);
  };

  f32x4 acc[4][4] = {};
  const int nt = K >> 5;

  stage(0, 0);
  for (int t = 0; t < nt; ++t) {
    const int cur = t & 1;
    if (t + 1 < nt) {
      stage(cur ^ 1, (t + 1) << 5);
      asm volatile("s_waitcnt vmcnt(4)" ::: "memory");
    } else {
      asm volatile("s_waitcnt vmcnt(0)" ::: "memory");
    }
    __builtin_amdgcn_s_barrier();
    asm volatile("" ::: "memory");

    bf16x8 af[4], bfr[4];
#pragma unroll
    for (int m = 0; m < 4; ++m) {
      const int row = wr * 64 + m * 16 + cc;
      af[m] = *(const bf16x8*)&As[cur][row * 32 + (cr ^ ((row >> 1) & 3)) * 8];
    }
#pragma unroll
    for (int n = 0; n < 4; ++n) {
      const int row = wc * 64 + n * 16 + cc;
      bfr[n] = *(const bf16x8*)&Bs[cur][row * 32 + (cr ^ ((row >> 1) & 3)) * 8];
    }
#pragma unroll
    for (int m = 0; m < 4; ++m)
#pragma unroll
      for (int n = 0; n < 4; ++n)
        acc[m][n] =
            __builtin_amdgcn_mfma_f32_16x16x32_bf16(af[m], bfr[n], acc[m][n], 0, 0, 0);

    asm volatile("" ::: "memory");
    __builtin_amdgcn_s_barrier();
  }

#pragma unroll
  for (int n = 0; n < 4; ++n) {
    const size_t col = n0 + wc * 64 + n * 16 + cc;
    const float bval = bias[col];
#pragma unroll
    for (int m = 0; m < 4; ++m) {
      const size_t row0_ = m0 + wr * 64 + m * 16 + cr * 4;
#pragma unroll
      for (int r = 0; r < 4; ++r) {
        const float val = acc[m][n][r] + bval;
        if constexpr (OUT_BF16)
          ((ushort*)Cp)[(row0_ + r) * N + col] = f2bf(val);
        else
          ((float*)Cp)[(row0_ + r) * N + col] = val;
      }
    }
  }
}

// ---- windowed attention ----------------------------------------------------
// grid = B*H*NW = 1024 blocks, 256 threads (4 waves x 64 q-rows).
// q/k/v: bf16 [B*S, D] with col = h*64+dk. Output written in-place over q.

__global__ __launch_bounds__(256) void attn_kernel(
    const ushort* __restrict__ q, const ushort* __restrict__ k,
    const ushort* __restrict__ v, ushort* __restrict__ x) {
  __shared__ ushort Ks[256 * 72];
  __shared__ ushort Vt[64 * 264];
  __shared__ ushort Pw[4][16 * 264];
  const int bid = blockIdx.x;
  const int w = bid & 15, h = (bid >> 4) & 15, b = bid >> 8;
  const int tid = threadIdx.x, lane = tid & 63, wv = tid >> 6;
  const int cc = lane & 15, cr = lane >> 4;
  const size_t base = ((size_t)b * 4096 + (size_t)w * 256) * 1024 + h * 64;

#pragma unroll
  for (int i = 0; i < 8; ++i) {
    const int ch = i * 256 + tid;
    const int row = ch >> 3, kc = ch & 7;
    bf16x8 val = *(const bf16x8*)(k + base + (size_t)row * 1024 + kc * 8);
    *(bf16x8*)&Ks[row * 72 + kc * 8] = val;
  }
  {
    const ushort* vp = v + base + (size_t)tid * 1024;
#pragma unroll
    for (int j = 0; j < 8; ++j) {
      bf16x8 vvv = *(const bf16x8*)(vp + j * 8);
#pragma unroll
      for (int e = 0; e < 8; ++e)
        Vt[(j * 8 + e) * 264 + tid] = __builtin_bit_cast(ushort, (__bf16)vvv[e]);
    }
  }
  __syncthreads();

  ushort* Pp = Pw[wv];
  for (int c = 0; c < 4; ++c) {
    const int qrow0 = wv * 64 + c * 16;
    const ushort* qp = q + base + (size_t)(qrow0 + cc) * 1024 + cr * 8;
    const bf16x8 qf0 = *(const bf16x8*)qp;
    const bf16x8 qf1 = *(const bf16x8*)(qp + 32);

    f32x4 sc[16];
#pragma unroll
    for (int cb = 0; cb < 16; ++cb) {
      const bf16x8 kb0 = *(const bf16x8*)&Ks[(cb * 16 + cc) * 72 + cr * 8];
      const bf16x8 kb1 = *(const bf16x8*)&Ks[(cb * 16 + cc) * 72 + 32 + cr * 8];
      f32x4 z = {0.f, 0.f, 0.f, 0.f};
      z = __builtin_amdgcn_mfma_f32_16x16x32_bf16(qf0, kb0, z, 0, 0, 0);
      z = __builtin_amdgcn_mfma_f32_16x16x32_bf16(qf1, kb1, z, 0, 0, 0);
      sc[cb] = z;
    }

    float inv[4];
#pragma unroll
    for (int r = 0; r < 4; ++r) {
      float mx = -1e30f;
#pragma unroll
      for (int cb = 0; cb < 16; ++cb) mx = fmaxf(mx, sc[cb][r]);
      mx = fmaxf(mx, __shfl_xor(mx, 1));
      mx = fmaxf(mx, __shfl_xor(mx, 2));
      mx = fmaxf(mx, __shfl_xor(mx, 4));
      mx = fmaxf(mx, __shfl_xor(mx, 8));
      float sum = 0.f;
#pragma unroll
      for (int cb = 0; cb < 16; ++cb) {
        const float p = __expf((sc[cb][r] - mx) * 0.125f);
        sc[cb][r] = p;
        sum += p;
      }
      sum += __shfl_xor(sum, 1);
      sum += __shfl_xor(sum, 2);
      sum += __shfl_xor(sum, 4);
      sum += __shfl_xor(sum, 8);
      inv[r] = 1.f / sum;
    }

#pragma unroll
    for (int r = 0; r < 4; ++r)
#pragma unroll
      for (int cb = 0; cb < 16; ++cb)
        Pp[(cr * 4 + r) * 264 + cb * 16 + cc] = f2bf(sc[cb][r]);

    bf16x8 pf[8];
#pragma unroll
    for (int ks = 0; ks < 8; ++ks)
      pf[ks] = *(const bf16x8*)&Pp[cc * 264 + ks * 32 + cr * 8];
    f32x4 o[4] = {};
#pragma unroll
    for (int db = 0; db < 4; ++db)
#pragma unroll
      for (int ks = 0; ks < 8; ++ks) {
        const bf16x8 bv = *(const bf16x8*)&Vt[(db * 16 + cc) * 264 + ks * 32 + cr * 8];
        o[db] = __builtin_amdgcn_mfma_f32_16x16x32_bf16(pf[ks], bv, o[db], 0, 0, 0);
      }

#pragma unroll
    for (int db = 0; db < 4; ++db)
#pragma unroll
      for (int r = 0; r < 4; ++r) {
        const int qr = qrow0 + cr * 4 + r;
        x[base + (size_t)qr * 1024 + db * 16 + cc] = f2bf(o[db][r] * inv[r]);
      }
  }
}

// ---- launch ----------------------------------------------------------------

extern "C" void kernel_launch(void* const* d_in, const int* in_sizes, int n_in,
                              void* d_out, int out_size, void* d_ws, size_t ws_size,
                              hipStream_t stream) {
  const float* query = (const float*)d_in[0];
  const float* key_  = (const float*)d_in[1];
  const float* value = (const float*)d_in[2];
  const float* Wq = (const float*)d_in[3];
  const float* bq = (const float*)d_in[4];
  const float* Wk = (const float*)d_in[5];
  const float* bk = (const float*)d_in[6];
  const float* Wv = (const float*)d_in[7];
  const float* bv = (const float*)d_in[8];
  const float* Wo = (const float*)d_in[9];
  const float* bo = (const float*)d_in[10];
  float* out = (float*)d_out;

  // ws: qb/kb/vb bf16 input copies + 4 bf16 weights + qp/kp/vp projections
  const size_t MN = (size_t)16384 * 1024;
  const size_t WN = (size_t)1024 * 1024;
  ushort* qb = (ushort*)d_ws;
  ushort* kb = qb + MN;
  ushort* vb = kb + MN;
  ushort* wqb = vb + MN;
  ushort* wkb = wqb + WN;
  ushort* wvb = wkb + WN;
  ushort* wob = wvb + WN;
  ushort* qp = wob + WN;
  ushort* kp = qp + MN;
  ushort* vp = kp + MN;

  const dim3 blk(256);
  const dim3 ggrid(128 * 8);  // 1024 workgroups, 4 resident blocks/CU

  cvt_qkv<<<dim3(3 * 2048), blk, 0, stream>>>(query, key_, value, qb, kb, vb);
  cvt_w<<<dim3(4 * 128), blk, 0, stream>>>(Wq, Wk, Wv, Wo, wqb, wkb, wvb, wob);

  gemm_2ph<1><<<ggrid, blk, 0, stream>>>(qb, wqb, bq, qp, 1024, 1024);
  gemm_2ph<1><<<ggrid, blk, 0, stream>>>(kb, wkb, bk, kp, 1024, 1024);
  gemm_2ph<1><<<ggrid, blk, 0, stream>>>(vb, wvb, bv, vp, 1024, 1024);

  attn_kernel<<<dim3(1024), blk, 0, stream>>>(qp, kp, vp, qp /*in-place*/);

  gemm_2ph<0><<<ggrid, blk, 0, stream>>>(qp, wob, bo, out, 1024, 1024);
}